// Round 7
// baseline (379.110 us; speedup 1.0000x reference)
//
#include <hip/hip_runtime.h>
#include <math.h>

#define NCANDK 10
#define PREDC  84
#define NCLS   80
#define TMAX   64   // LDS capacity for targets (T=50 actual)
#define RTHREADS 512                  // kROW block size (8 waves)
#define RWAVES   8
#define RSLOTS   (RWAVES * NCANDK)    // 80 fallback candidates per row
#define WROWS  85   // padded LDS row stride for staged anchors (2-way max)

// fast softplus: max(z,0) + ln2 * log2(1 + exp2(-z*log2e)); |err| ~2e-7
__device__ __forceinline__ float softplus_f(float z) {
    const float e = __builtin_amdgcn_exp2f(-1.4426950408889634f * fabsf(z));
    return fmaxf(z, 0.0f) + 0.6931471805599453f * __builtin_amdgcn_logf(1.0f + e);
}

// 3*(-ln(x)) = -3ln2 * log2(x)
__device__ __forceinline__ float neg3ln_f(float x) {
    return -2.0794415416798357f * __builtin_amdgcn_logf(x);
}

// Anchor index -> (xc, yc, stride). Exact: levels (8,160),(16,80),(32,40);
// magic-mul div exact over range; bitwise == (grid+0.5f)*stride (validated r5).
__device__ __forceinline__ float3 anchor_geom(int a) {
    int r; float st; unsigned M, n;
    if (a < 25600)      { r = a;         st = 8.0f;  M = 104858u; n = 160u; }
    else if (a < 32000) { r = a - 25600; st = 16.0f; M = 209716u; n = 80u;  }
    else                { r = a - 32000; st = 32.0f; M = 419431u; n = 40u;  }
    const unsigned gy = ((unsigned)r * M) >> 24;
    const unsigned gx = (unsigned)r - gy * n;
    return make_float3(((float)gx + 0.5f) * st, ((float)gy + 0.5f) * st, st);
}

// ---------------------------------------------------------------------------
// Kernel A (v7): coalesced wave-private staging + R6's transposed IoU phase.
//  Per wave: 4 rounds of 16 anchors. Each round:
//   - 336 float4 loaded LINEARLY (16B/lane contiguous, fully coalesced)
//     into a wave-private LDS tile (rows padded to 85 floats -> <=2-way).
//   - lane = (anchor&15, quarter): 20 sequential softplus per lane,
//     fold ((p0+p1)+p2)+p3 via __shfl (exact validated 4x20 left fold).
//   - q==0 lanes write box4 (coalesced 256B) + raw box/S into LDS tables.
//  Then per-lane geometry (anyB/anyC) -> metaS/cnt/mint; mask bxb/bxa;
//  then R6's IoU phase: lane = target, broadcast-read the wave's 64 anchors,
//  guarded top-10 insertion, coalesced tI write. Barriers are cheap/symmetric.
// ---------------------------------------------------------------------------
__global__ void __launch_bounds__(256) kA(
    const float* __restrict__ pred, const float* __restrict__ target,
    const float* __restrict__ grid, const float* __restrict__ strd,
    float4* __restrict__ box4, float* __restrict__ metaS,
    int* __restrict__ cnt, int* __restrict__ mint,
    float* __restrict__ tI, int A, int T, int ntile)
{
    const int b    = blockIdx.y;
    const int tid  = threadIdx.x;
    const int w    = tid >> 6;
    const int lane = tid & 63;

    __shared__ float  tg[TMAX * 5];
    __shared__ float  wt[4][16 * WROWS];   // wave-private staging tiles
    __shared__ float4 bxb[256];            // masked anchor boxes for IoU phase
    __shared__ float  bxa[256];            // masked areas
    __shared__ float  sS[256];             // per-anchor softplus sums

    const float* tb = target + (size_t)b * T * 5;
    for (int i = tid; i < T * 5; i += 256) tg[i] = tb[i];
    __syncthreads();

    const int blockBase = blockIdx.x * 256;
    const int waveBase  = blockBase + w * 64;
    float* wrow = wt[w];

    // ---- 4 rounds x 16 anchors: coalesced stage + softplus fold ----
    for (int r = 0; r < 4; ++r) {
        const int aBase = waveBase + r * 16;
        const float4* src = (const float4*)(pred + ((size_t)b * A + aBase) * PREDC);
#pragma unroll
        for (int it = 0; it < 6; ++it) {
            const int f = lane + it * 64;
            if (f < 336) {                       // 16 anchors * 21 float4
                const int an = f / 21;           // anchor within round
                const int fe = f - an * 21;      // float4 within anchor
                float4 v = make_float4(0.0f, 0.0f, 0.0f, 0.0f);
                if (aBase + an < A) v = src[f];
                float* d = wrow + an * WROWS + fe * 4;
                d[0] = v.x; d[1] = v.y; d[2] = v.z; d[3] = v.w;
            }
        }
        __syncthreads();   // tile ready (symmetric across waves, cheap)

        const int al = lane & 15;
        const int q  = lane >> 4;
        const float* row = wrow + al * WROWS;
        float p = 0.0f;
        const int c0 = 4 + q * 20;
#pragma unroll
        for (int c = 0; c < 20; ++c) p += softplus_f(row[c0 + c]);

        const float p1 = __shfl(p, al + 16);
        const float p2 = __shfl(p, al + 32);
        const float p3 = __shfl(p, al + 48);
        if (q == 0) {
            const float S = fmaxf(((p + p1) + p2) + p3, 1e-30f);  // 4x20 left fold
            const int sid = w * 64 + r * 16 + al;
            sS[sid] = S;
            const float4 box = make_float4(row[0], row[1], row[2], row[3]);
            bxb[sid] = box;                      // raw; masked after geometry
            const int ga = aBase + al;
            if (ga < A) box4[(size_t)b * A + ga] = box;
        }
        __syncthreads();   // before next round overwrites wt
    }

    // ---- geometry per lane (lane = wave-local anchor) ----
    const int ga    = blockBase + tid;
    bool iba = false;
    if (ga < A) {
        const float2 g2 = ((const float2*)grid)[ga];
        const float  st = strd[ga];
        const float  xc = (g2.x + 0.5f) * st, yc = (g2.y + 0.5f) * st;
        const float  rad = 2.5f * st;
        bool anyB = false, anyC = false;
        for (int t = 0; t < T; ++t) {
            const float x0 = tg[t * 5 + 1], y0 = tg[t * 5 + 2];
            const float x1 = tg[t * 5 + 3], y1 = tg[t * 5 + 4];
            anyB = anyB || (fminf(fminf(xc - x0, yc - y0), fminf(x1 - xc, y1 - yc)) > 0.0f);
            const float cx = (x0 + x1) * 0.5f, cy = (y0 + y1) * 0.5f;
            anyC = anyC || (fmaxf(fabsf(xc - cx), fabsf(yc - cy)) < rad);
        }
        const float S = sS[tid];
        const float m = (anyB || anyC) ? S : -S;
        const size_t ba = (size_t)b * A + ga;
        metaS[ba] = m;
        cnt[ba]   = 0;
        mint[ba]  = T;
        iba = (m > 0.0f);
    }

    // mask anchor tables (degenerate -> iou == +0 exactly)
    if (iba) {
        const float4 rb = bxb[tid];
        bxa[tid] = (rb.z - rb.x) * (rb.w - rb.y);
    } else {
        bxb[tid] = make_float4(INFINITY, INFINITY, -INFINITY, -INFINITY);
        bxa[tid] = INFINITY;
    }
    __syncthreads();

    // ---- IoU phase: lane = target, loop wave's 64 anchors (broadcast) ----
    if (lane < T) {
        const float x0 = tg[lane * 5 + 1], y0 = tg[lane * 5 + 2];
        const float x1 = tg[lane * 5 + 3], y1 = tg[lane * 5 + 4];
        const float area_t = (x1 - x0) * (y1 - y0);

        float L0,L1,L2,L3,L4,L5,L6,L7,L8,L9;
        L0=L1=L2=L3=L4=L5=L6=L7=L8=L9 = 0.0f;

        const int ab = w * 64;
#pragma unroll 4
        for (int a = 0; a < 64; ++a) {
            const float4 pb = bxb[ab + a];     // wave-uniform: broadcast
            const float aap = bxa[ab + a];
            const float lx = fmaxf(x0, pb.x), ly = fmaxf(y0, pb.y);
            const float rx = fminf(x1, pb.z), ry = fminf(y1, pb.w);
            const float ww = fmaxf(rx - lx, 0.0f), hh = fmaxf(ry - ly, 0.0f);
            const float inter = ww * hh;
            const float uni = area_t + aap - inter;
            const float v = inter / fmaxf(uni, 1e-9f);
            if (v > L9) {
                float x = v;
                { const float o = L0; const bool tk = x > o; L0 = tk ? x : o; x = tk ? o : x; }
                { const float o = L1; const bool tk = x > o; L1 = tk ? x : o; x = tk ? o : x; }
                { const float o = L2; const bool tk = x > o; L2 = tk ? x : o; x = tk ? o : x; }
                { const float o = L3; const bool tk = x > o; L3 = tk ? x : o; x = tk ? o : x; }
                { const float o = L4; const bool tk = x > o; L4 = tk ? x : o; x = tk ? o : x; }
                { const float o = L5; const bool tk = x > o; L5 = tk ? x : o; x = tk ? o : x; }
                { const float o = L6; const bool tk = x > o; L6 = tk ? x : o; x = tk ? o : x; }
                { const float o = L7; const bool tk = x > o; L7 = tk ? x : o; x = tk ? o : x; }
                { const float o = L8; const bool tk = x > o; L8 = tk ? x : o; x = tk ? o : x; }
                { const float o = L9; const bool tk = x > o; L9 = tk ? x : o; x = tk ? o : x; }
            }
        }
        // coalesced per-wave write: [b][slot = blockIdx.x*4+w][t][10]
        float* dst = tI + ((((size_t)b * (ntile * 4)) + (blockIdx.x * 4 + w)) * T
                           + lane) * NCANDK;
        dst[0]=L0; dst[1]=L1; dst[2]=L2; dst[3]=L3; dst[4]=L4;
        dst[5]=L5; dst[6]=L6; dst[7]=L7; dst[8]=L8; dst[9]=L9;
    }
}

// ---------------------------------------------------------------------------
// insertion networks (per-lane top-10 registers)
// ---------------------------------------------------------------------------
#define IOU_INS(J) { const float o = i##J; const bool tk = v > o; \
                     i##J = tk ? v : o; v = tk ? o : v; }
#define CST_INS(J) { const float oc = c##J; const int oi = q##J; \
                     const bool tk = (v < oc) || (v == oc && vi < oi); \
                     c##J = tk ? v : oc; q##J = tk ? vi : oi; \
                     v = tk ? oc : v; vi = tk ? oi : vi; }
#define IOU_POP { i0=i1; i1=i2; i2=i3; i3=i4; i4=i5; i5=i6; i6=i7; i7=i8; i8=i9; i9=0.0f; }
#define CST_POP { c0=c1; c1=c2; c2=c3; c3=c4; c4=c5; c5=c6; c6=c7; c7=c8; c8=c9; c9=INFINITY; \
                  q0=q1; q1=q2; q2=q3; q3=q4; q4=q5; q5=q6; q6=q7; q7=q8; q8=q9; q9=0x7fffffff; }

// ---------------------------------------------------------------------------
// kCTR helper: one candidate center-window cell -> (cost, idx, is_group1)
// ---------------------------------------------------------------------------
__device__ __forceinline__ void ctr_item(
    int id, const float* pb, const float4* bx, const float* ms,
    int cls, float x0, float y0, float x1, float y1,
    float cx, float cy, float area_t,
    float& cost, int& idx, bool& g1)
{
    cost = INFINITY; idx = 0x7fffffff; g1 = false;
    int levn, base; float s;
    if (id < 36)      { levn = 160; base = 0;     s = 8.0f;  }
    else if (id < 72) { levn = 80;  base = 25600; s = 16.0f; id -= 36; }
    else              { levn = 40;  base = 32000; s = 32.0f; id -= 72; }
    const int dy = id / 6, dx = id - dy * 6;
    const int gx = (int)floorf(cx / s - 3.0f) + dx;
    const int gy = (int)floorf(cy / s - 3.0f) + dy;
    if (gx < 0 || gx >= levn || gy < 0 || gy >= levn) return;
    const int a = base + gy * levn + gx;
    const float xc = ((float)gx + 0.5f) * s, yc = ((float)gy + 0.5f) * s;
    const bool inc = fmaxf(fabsf(xc - cx), fabsf(yc - cy)) < 2.5f * s;
    const bool inb = fminf(fminf(xc - x0, yc - y0), fminf(x1 - xc, y1 - yc)) > 0.0f;
    if (!(inc && inb)) return;
    const float4 pbox = bx[a];
    const float lx = fmaxf(x0, pbox.x), ly = fmaxf(y0, pbox.y);
    const float rx = fminf(x1, pbox.z), ry = fminf(y1, pbox.w);
    const float w = fmaxf(rx - lx, 0.0f), h = fmaxf(ry - ly, 0.0f);
    const float inter  = w * h;
    const float area_p = (pbox.z - pbox.x) * (pbox.w - pbox.y);
    const float uni = area_t + area_p - inter;
    const float iou = inter / fmaxf(uni, 1e-9f);
    const float S  = fabsf(ms[a]);
    const float zs = pb[(size_t)a * PREDC + 4 + cls];
    cost = (S - zs) + neg3ln_f(iou + 1e-8f);
    idx = a; g1 = true;
}

// ---------------------------------------------------------------------------
// kROW: per-(b,t) row kernel — no anchor scan.
//   Phase B (wave 0): center-window enumeration -> ctr top-10 cost + g1cnt;
//   Phase B'(wave 1, concurrent): merge tI row (ntile*4*10 values) -> dyn_k.
//   Phase C (all 8 waves, rare): full-A cost scan fallback (exact g3 prune).
//   Phase D: first dyn_k lanes scatter atomics into cnt/mint.
// ---------------------------------------------------------------------------
__global__ void __launch_bounds__(RTHREADS) kROW(
    const float* __restrict__ pred, const float* __restrict__ target,
    const float4* __restrict__ box4, const float* __restrict__ metaS,
    const float* __restrict__ tI,
    int* __restrict__ cnt, int* __restrict__ mint, int A, int T, int ntile)
{
    const int t    = blockIdx.x;
    const int b    = blockIdx.y;
    const int tid  = threadIdx.x;
    const int wid  = tid >> 6;
    const int lane = tid & 63;
    const int row  = b * T + t;

    __shared__ float sC[RSLOTS];
    __shared__ int   sX[RSLOTS];
    __shared__ float fC[NCANDK];
    __shared__ int   fX[NCANDK];
    __shared__ int   sFlag, sDk;

    const float* tb = target + (size_t)row * 5;
    const int   cls = (int)tb[0];
    const float x0 = tb[1], y0 = tb[2], x1 = tb[3], y1 = tb[4];
    const float area_t = (x1 - x0) * (y1 - y0);
    const float cx = (x0 + x1) * 0.5f, cy = (y0 + y1) * 0.5f;

    const float*  pb = pred  + (size_t)b * A * PREDC;
    const float4* bx = box4  + (size_t)b * A;
    const float*  ms = metaS + (size_t)b * A;

    // ---- Phase B (wave 0): center-window candidates; B' (wave 1): dyn_k ----
    if (wid == 0) {
        float e0c, e1c; int e0x, e1x; bool g0, g1b;
        ctr_item(lane, pb, bx, ms, cls, x0, y0, x1, y1, cx, cy, area_t, e0c, e0x, g0);
        if (lane < 44) {
            ctr_item(lane + 64, pb, bx, ms, cls, x0, y0, x1, y1, cx, cy, area_t, e1c, e1x, g1b);
        } else { e1c = INFINITY; e1x = 0x7fffffff; g1b = false; }

        const int g1cnt = __popcll(__ballot(g0)) + __popcll(__ballot(g1b));

        if (e1c < e0c || (e1c == e0c && e1x < e0x)) {
            const float tc = e0c; e0c = e1c; e1c = tc;
            const int   tx = e0x; e0x = e1x; e1x = tx;
        }
#pragma unroll
        for (int r = 0; r < NCANDK; ++r) {
            float v = e0c; int vi = e0x;
#pragma unroll
            for (int off = 32; off > 0; off >>= 1) {
                const float ov = __shfl_xor(v, off);
                const int   oi = __shfl_xor(vi, off);
                if (ov < v || (ov == v && oi < vi)) { v = ov; vi = oi; }
            }
            if (lane == 0) { fC[r] = v; fX[r] = vi; }
            if (e0x == vi) { e0c = e1c; e0x = e1x; e1c = INFINITY; e1x = 0x7fffffff; }
        }
        if (lane == 0) sFlag = (g1cnt >= NCANDK) ? 0 : 1;
    } else if (wid == 1) {
        // merge the row's ntile*4*10 iou values -> dyn_k
        const int NT4 = ntile * 4;
        const int n   = NT4 * NCANDK;
        float i0,i1,i2,i3,i4,i5,i6,i7,i8,i9;
        i0=i1=i2=i3=i4=i5=i6=i7=i8=i9 = 0.0f;
        for (int i = lane; i < n; i += 64) {
            const int gw = i / NCANDK;
            const int r  = i - gw * NCANDK;
            float v = tI[(((size_t)b * NT4 + gw) * T + t) * NCANDK + r];
            if (v > i9) {
                IOU_INS(0) IOU_INS(1) IOU_INS(2) IOU_INS(3) IOU_INS(4)
                IOU_INS(5) IOU_INS(6) IOU_INS(7) IOU_INS(8) IOU_INS(9)
            }
        }
        float ssum = 0.0f;
#pragma unroll
        for (int r = 0; r < NCANDK; ++r) {
            float v = i0; int vl = lane;
#pragma unroll
            for (int off = 32; off > 0; off >>= 1) {
                const float ov = __shfl_xor(v, off);
                const int   ol = __shfl_xor(vl, off);
                if (ov > v || (ov == v && ol < vl)) { v = ov; vl = ol; }
            }
            ssum += v;                   // descending order == reference sum
            if (lane == vl) IOU_POP
        }
        if (lane == 0) {
            int k = (int)ssum;           // trunc == astype(int32) for >=0
            k = k < 1 ? 1 : (k > NCANDK ? NCANDK : k);
            sDk = k;
        }
    }
    __syncthreads();

    // ---- Phase C: rare full-A fallback cost scan (exact g3 prune) ----
    if (sFlag) {
        float c0,c1,c2,c3,c4,c5,c6,c7,c8,c9;
        int   q0,q1,q2,q3,q4,q5,q6,q7,q8,q9;
        c0=c1=c2=c3=c4=c5=c6=c7=c8=c9 = INFINITY;
        q0=q1=q2=q3=q4=q5=q6=q7=q8=q9 = 0x7fffffff;

        for (int a = tid; a < A; a += RTHREADS) {
            const float m     = ms[a];
            const bool  ibanc = m > 0.0f;
            // exact prune: non-iba cost >= 1e9 - |base| (|base| << 1e6);
            // cannot enter a top-10 whose current worst is < 0.999e9.
            if (!ibanc && c9 < 0.999e9f) continue;

            const float4 pbox = bx[a];
            const float  s    = fabsf(m);
            const float  zsel = pb[(size_t)a * PREDC + 4 + cls];
            const float3 g    = anchor_geom(a);

            const float lx = fmaxf(x0, pbox.x), ly = fmaxf(y0, pbox.y);
            const float rx = fminf(x1, pbox.z), ry = fminf(y1, pbox.w);
            const float w = fmaxf(rx - lx, 0.0f), h = fmaxf(ry - ly, 0.0f);
            const float inter  = w * h;
            const float area_p = (pbox.z - pbox.x) * (pbox.w - pbox.y);
            const float uni = area_t + area_p - inter;
            const float iou = inter / fmaxf(uni, 1e-9f);

            const bool inb = fminf(fminf(g.x - x0, g.y - y0), fminf(x1 - g.x, y1 - g.y)) > 0.0f;
            const bool inc = fmaxf(fabsf(g.x - cx), fabsf(g.y - cy)) < 2.5f * g.z;

            float cost = (s - zsel) + neg3ln_f(iou + 1e-8f);
            cost = cost + 1e5f * ((inb && inc) ? 0.0f : 1.0f);
            cost = cost + 1e9f * (ibanc ? 0.0f : 1.0f);

            if (cost < c9 || (cost == c9 && a < q9)) {
                float v = cost; int vi = a;
                CST_INS(0) CST_INS(1) CST_INS(2) CST_INS(3) CST_INS(4)
                CST_INS(5) CST_INS(6) CST_INS(7) CST_INS(8) CST_INS(9)
            }
        }
#pragma unroll
        for (int r = 0; r < NCANDK; ++r) {
            float v = c0; int vi = q0;
#pragma unroll
            for (int off = 32; off > 0; off >>= 1) {
                const float ov = __shfl_xor(v, off);
                const int   oi = __shfl_xor(vi, off);
                if (ov < v || (ov == v && oi < vi)) { v = ov; vi = oi; }
            }
            if (lane == 0) { sC[wid * NCANDK + r] = v; sX[wid * NCANDK + r] = vi; }
            if (q0 == vi) CST_POP
        }
        __syncthreads();
        if (wid == 0) {
            float v0c = sC[lane]; int v0x = sX[lane];
            float v1c = (lane < RSLOTS - 64) ? sC[64 + lane] : INFINITY;
            int   v1x = (lane < RSLOTS - 64) ? sX[64 + lane] : 0x7fffffff;
            if (v1c < v0c || (v1c == v0c && v1x < v0x)) {
                const float tc = v0c; v0c = v1c; v1c = tc;
                const int   tx = v0x; v0x = v1x; v1x = tx;
            }
#pragma unroll
            for (int r = 0; r < NCANDK; ++r) {
                float v = v0c; int vi = v0x;
#pragma unroll
                for (int off = 32; off > 0; off >>= 1) {
                    const float ov = __shfl_xor(v, off);
                    const int   oi = __shfl_xor(vi, off);
                    if (ov < v || (ov == v && oi < vi)) { v = ov; vi = oi; }
                }
                if (lane == 0) { fC[r] = v; fX[r] = vi; }
                if (v0x == vi) { v0c = v1c; v0x = v1x; v1c = INFINITY; v1x = 0x7fffffff; }
            }
        }
        __syncthreads();
    }

    // ---- Phase D: scatter first dyn_k candidates (iba-masked) ----
    if (tid < sDk) {
        const int aw = fX[tid];
        if (aw != 0x7fffffff && ms[aw] > 0.0f) {
            const size_t base = (size_t)b * A;
            atomicAdd(&cnt[base + aw], 1);
            atomicMin(&mint[base + aw], t);
        }
    }
}

// ---------------------------------------------------------------------------
// Kernel C: per (b, a) — resolve matches, conflicts, write outputs.
// Output layout (floats): mm[BA] | bt[BA*4] | ot[BA] | ct[BA]
// ---------------------------------------------------------------------------
__global__ void __launch_bounds__(256) kC(
    const float* __restrict__ pred, const float* __restrict__ target,
    const float4* __restrict__ box4, const float* __restrict__ metaS,
    const int* __restrict__ cnt, const int* __restrict__ mint,
    float* __restrict__ out, int A, int T, long BAl)
{
    const int b = blockIdx.y;
    const int a = blockIdx.x * blockDim.x + threadIdx.x;
    __shared__ float tg[TMAX * 5];
    const float* tb = target + (size_t)b * T * 5;
    for (int i = threadIdx.x; i < T * 5; i += blockDim.x) tg[i] = tb[i];
    __syncthreads();
    if (a >= A) return;

    const size_t ba = (size_t)b * A + a;
    const size_t BA = (size_t)BAl;
    float*  out_mm = out;
    float4* out_bt = (float4*)(out + BA);
    float*  out_ot = out + 5 * BA;
    float*  out_ct = out + 6 * BA;

    const int c = cnt[ba];
    if (c == 0) {
        out_mm[ba] = 0.0f;
        out_bt[ba] = make_float4(0.0f, 0.0f, 0.0f, 0.0f);
        out_ot[ba] = 0.0f;
        out_ct[ba] = (float)NCLS;
        return;
    }

    const float4 pbox = box4[ba];
    const float area_p = (pbox.z - pbox.x) * (pbox.w - pbox.y);

    const bool conflict = (c > 1);
    const float* p = pred + ba * PREDC;  // only dereferenced if conflict
    float sA = 0.0f, xc = 0.0f, yc = 0.0f, stv = 0.0f;
    int ibanc = 1;
    if (conflict) {
        const float m = metaS[ba];
        sA = fabsf(m);
        ibanc = m > 0.0f ? 1 : 0;
        const float3 g = anchor_geom(a);
        xc = g.x; yc = g.y; stv = g.z;
    }

    float pmax = 0.0f;
    float bestc = INFINITY; int bestt = 0;
    for (int t = 0; t < T; ++t) {
        const float x0 = tg[t * 5 + 1], y0 = tg[t * 5 + 2];
        const float x1 = tg[t * 5 + 3], y1 = tg[t * 5 + 4];
        const float lx = fmaxf(x0, pbox.x), ly = fmaxf(y0, pbox.y);
        const float rx = fminf(x1, pbox.z), ry = fminf(y1, pbox.w);
        const float w = fmaxf(rx - lx, 0.0f), h = fmaxf(ry - ly, 0.0f);
        const float inter  = w * h;
        const float area_t = (x1 - x0) * (y1 - y0);
        const float uni = area_t + area_p - inter;
        const float iou = inter / fmaxf(uni, 1e-9f);
        pmax = fmaxf(pmax, iou);
        if (conflict) {
            const bool inb = fminf(fminf(xc - x0, yc - y0), fminf(x1 - xc, y1 - yc)) > 0.0f;
            const float cxt = (x0 + x1) * 0.5f, cyt = (y0 + y1) * 0.5f;
            const bool inc = fmaxf(fabsf(xc - cxt), fabsf(yc - cyt)) < 2.5f * stv;
            const float zsel = p[4 + (int)tg[t * 5]];
            float cost = (sA - zsel) + neg3ln_f(iou + 1e-8f);
            cost = cost + 1e5f * ((inb && inc) ? 0.0f : 1.0f);
            cost = cost + 1e9f * (ibanc ? 0.0f : 1.0f);
            if (cost < bestc) { bestc = cost; bestt = t; }
        }
    }
    const int tp = conflict ? bestt : mint[ba];

    out_mm[ba] = 1.0f;
    out_bt[ba] = make_float4(tg[tp * 5 + 1], tg[tp * 5 + 2], tg[tp * 5 + 3], tg[tp * 5 + 4]);
    out_ot[ba] = pmax;
    out_ct[ba] = tg[tp * 5 + 0];
}

// ---------------------------------------------------------------------------
extern "C" void kernel_launch(void* const* d_in, const int* in_sizes, int n_in,
                              void* d_out, int out_size, void* d_ws, size_t ws_size,
                              hipStream_t stream)
{
    const float* pred   = (const float*)d_in[0];
    const float* target = (const float*)d_in[1];
    const float* grid   = (const float*)d_in[2];
    const float* strd   = (const float*)d_in[3];

    const int A = in_sizes[3];
    const int B = in_sizes[0] / (A * PREDC);
    const int T = in_sizes[1] / (B * 5);
    const size_t BA = (size_t)B * A;
    const int ntile = (A + 255) / 256;   // 256-anchor blocks (= kA grid.x)

    // ws: box4[BA] | metaS[BA] | cnt[BA] | mint[BA] | tI[B*ntile*4*T*10]
    float4* box4  = (float4*)d_ws;
    float*  metaS = (float*)(box4 + BA);
    int*    cnt   = (int*)(metaS + BA);
    int*    mint  = cnt + BA;
    float*  tIb   = (float*)(mint + BA);

    float* out = (float*)d_out;

    dim3 gA(ntile, B);
    kA<<<gA, 256, 0, stream>>>(pred, target, grid, strd, box4, metaS, cnt, mint,
                               tIb, A, T, ntile);

    dim3 gR(T, B);
    kROW<<<gR, RTHREADS, 0, stream>>>(pred, target, box4, metaS, tIb,
                                      cnt, mint, A, T, ntile);

    dim3 gC((A + 255) / 256, B);
    kC<<<gC, 256, 0, stream>>>(pred, target, box4, metaS, cnt, mint, out, A, T, (long)BA);
}

// Round 8
// 363.986 us; speedup vs baseline: 1.0416x; 1.0416x over previous
//
#include <hip/hip_runtime.h>
#include <math.h>

#define NCANDK 10
#define PREDC  84
#define NCLS   80
#define TMAX   64   // LDS capacity for targets (T=50 actual)
#define RTHREADS 512                  // kROW block size (8 waves)
#define RWAVES   8
#define RSLOTS   (RWAVES * NCANDK)    // 80 fallback candidates per row

typedef unsigned int u32;

// async global->LDS, 16B per lane: dest = uniform base + lane*16 (HW rule)
__device__ __forceinline__ void gload16(const void* g, void* l) {
    __builtin_amdgcn_global_load_lds(
        (const __attribute__((address_space(1))) u32*)g,
        (__attribute__((address_space(3))) u32*)l, 16, 0, 0);
}

// fast softplus: max(z,0) + ln2 * log2(1 + exp2(-z*log2e)); |err| ~2e-7
__device__ __forceinline__ float softplus_f(float z) {
    const float e = __builtin_amdgcn_exp2f(-1.4426950408889634f * fabsf(z));
    return fmaxf(z, 0.0f) + 0.6931471805599453f * __builtin_amdgcn_logf(1.0f + e);
}

// 3*(-ln(x)) = -3ln2 * log2(x)
__device__ __forceinline__ float neg3ln_f(float x) {
    return -2.0794415416798357f * __builtin_amdgcn_logf(x);
}

// Anchor index -> (xc, yc, stride). Exact: levels (8,160),(16,80),(32,40);
// magic-mul div exact over range; bitwise == (grid+0.5f)*stride (validated r5).
__device__ __forceinline__ float3 anchor_geom(int a) {
    int r; float st; unsigned M, n;
    if (a < 25600)      { r = a;         st = 8.0f;  M = 104858u; n = 160u; }
    else if (a < 32000) { r = a - 25600; st = 16.0f; M = 209716u; n = 80u;  }
    else                { r = a - 32000; st = 32.0f; M = 419431u; n = 40u;  }
    const unsigned gy = ((unsigned)r * M) >> 24;
    const unsigned gx = (unsigned)r - gy * n;
    return make_float3(((float)gx + 0.5f) * st, ((float)gy + 0.5f) * st, st);
}

// ---------------------------------------------------------------------------
// Kernel A (v8): async global_load_lds staging, wave-private rounds (no
// barriers in the staging loop), exact 4x20 softplus fold via __shfl,
// R6's transposed IoU phase. Only 2 __syncthreads() in the whole kernel.
//  Per wave: 4 rounds x 16 anchors:
//   - 6x global_load_lds width=16 (each 1KB fully coalesced, linear LDS)
//   - s_waitcnt vmcnt(0) (same-wave produce->consume; no barrier needed)
//   - lane=(al,q): 20 sequential softplus from LDS (16B-aligned ->
//     ds_read_b128), fold ((p0+p1)+p2)+p3 via __shfl  [bitwise-validated]
//   - q==0: S -> sS, box -> bxb + coalesced box4 store
//  OOB anchors: clamp SOURCE address (no fault); garbage is masked later.
// ---------------------------------------------------------------------------
__global__ void __launch_bounds__(256) kA(
    const float* __restrict__ pred, const float* __restrict__ target,
    const float* __restrict__ grid, const float* __restrict__ strd,
    float4* __restrict__ box4, float* __restrict__ metaS,
    int* __restrict__ cnt, int* __restrict__ mint,
    float* __restrict__ tI, int A, int T, int ntile)
{
    const int b    = blockIdx.y;
    const int tid  = threadIdx.x;
    const int w    = tid >> 6;
    const int lane = tid & 63;

    __shared__ float  tg[TMAX * 5];
    __shared__ float  wt[4][16 * 84];   // wave-private linear staging tiles
    __shared__ float4 bxb[256];
    __shared__ float  bxa[256];
    __shared__ float  sS[256];

    const float* tb = target + (size_t)b * T * 5;
    for (int i = tid; i < T * 5; i += 256) tg[i] = tb[i];

    const int blockBase = blockIdx.x * 256;
    const int waveBase  = blockBase + w * 64;
    const float4* gp    = (const float4*)pred;
    const size_t  imgF4 = (size_t)b * A * 21;   // pred f4 base of image b
    float* wrow = wt[w];

    for (int r = 0; r < 4; ++r) {
        const int aBase = waveBase + r * 16;
        if (aBase >= A) break;                  // wave-uniform

        const size_t baseF4 = imgF4 + (size_t)aBase * 21;
        // 336 f4 per round: 5 full wave-loads + 1 partial (16 lanes)
#pragma unroll
        for (int k = 0; k < 5; ++k) {
            const int f  = k * 64 + lane;
            const int an = f / 21;
            const size_t gf4 = baseF4 + ((aBase + an < A) ? (size_t)f : 0);
            gload16(gp + gf4, wrow + k * 256);          // k*64 f4 = k*256 floats
        }
        if (lane < 16) {
            const int f  = 320 + lane;
            const int an = f / 21;                       // 15, valid check
            const size_t gf4 = baseF4 + ((aBase + an < A) ? (size_t)f : 0);
            gload16(gp + gf4, wrow + 5 * 256);
        }
        asm volatile("s_waitcnt vmcnt(0)" ::: "memory");

        const int al = lane & 15;
        const int q  = lane >> 4;
        const float* row = wrow + al * 84;
        float p = 0.0f;
        const int c0 = 4 + q * 20;
#pragma unroll
        for (int c = 0; c < 20; ++c) p += softplus_f(row[c0 + c]);

        const float p1 = __shfl(p, al + 16);
        const float p2 = __shfl(p, al + 32);
        const float p3 = __shfl(p, al + 48);
        if (q == 0) {
            const float S = fmaxf(((p + p1) + p2) + p3, 1e-30f);  // 4x20 left fold
            const int sid = w * 64 + r * 16 + al;
            sS[sid]  = S;
            bxb[sid] = make_float4(row[0], row[1], row[2], row[3]);
            const int ga = aBase + al;
            if (ga < A) box4[(size_t)b * A + ga] = bxb[sid];
        }
        // no barrier: same-wave LDS produce->consume; next round's loads are
        // ordered after these reads by data dependence + alias conservatism
    }
    __syncthreads();   // publish tg/sS/bxb for the block phases below

    // ---- geometry per thread (thread = block-local anchor) ----
    const int ga = blockBase + tid;
    bool iba = false;
    if (ga < A) {
        const float2 g2 = ((const float2*)grid)[ga];
        const float  st = strd[ga];
        const float  xc = (g2.x + 0.5f) * st, yc = (g2.y + 0.5f) * st;
        const float  rad = 2.5f * st;
        bool anyB = false, anyC = false;
        for (int t = 0; t < T; ++t) {
            const float x0 = tg[t * 5 + 1], y0 = tg[t * 5 + 2];
            const float x1 = tg[t * 5 + 3], y1 = tg[t * 5 + 4];
            anyB = anyB || (fminf(fminf(xc - x0, yc - y0), fminf(x1 - xc, y1 - yc)) > 0.0f);
            const float cx = (x0 + x1) * 0.5f, cy = (y0 + y1) * 0.5f;
            anyC = anyC || (fmaxf(fabsf(xc - cx), fabsf(yc - cy)) < rad);
        }
        const float S = sS[tid];
        const float m = (anyB || anyC) ? S : -S;
        const size_t ba = (size_t)b * A + ga;
        metaS[ba] = m;
        cnt[ba]   = 0;
        mint[ba]  = T;
        iba = (m > 0.0f);
    }

    // mask anchor tables (degenerate -> iou == +0 exactly; covers OOB/garbage)
    if (iba) {
        const float4 rb = bxb[tid];
        bxa[tid] = (rb.z - rb.x) * (rb.w - rb.y);
    } else {
        bxb[tid] = make_float4(INFINITY, INFINITY, -INFINITY, -INFINITY);
        bxa[tid] = INFINITY;
    }
    __syncthreads();

    // ---- IoU phase: lane = target, loop wave's 64 anchors (broadcast) ----
    if (lane < T) {
        const float x0 = tg[lane * 5 + 1], y0 = tg[lane * 5 + 2];
        const float x1 = tg[lane * 5 + 3], y1 = tg[lane * 5 + 4];
        const float area_t = (x1 - x0) * (y1 - y0);

        float L0,L1,L2,L3,L4,L5,L6,L7,L8,L9;
        L0=L1=L2=L3=L4=L5=L6=L7=L8=L9 = 0.0f;

        const int ab = w * 64;
#pragma unroll 4
        for (int a = 0; a < 64; ++a) {
            const float4 pb = bxb[ab + a];     // wave-uniform: broadcast
            const float aap = bxa[ab + a];
            const float lx = fmaxf(x0, pb.x), ly = fmaxf(y0, pb.y);
            const float rx = fminf(x1, pb.z), ry = fminf(y1, pb.w);
            const float ww = fmaxf(rx - lx, 0.0f), hh = fmaxf(ry - ly, 0.0f);
            const float inter = ww * hh;
            const float uni = area_t + aap - inter;
            const float v = inter / fmaxf(uni, 1e-9f);
            if (v > L9) {
                float x = v;
                { const float o = L0; const bool tk = x > o; L0 = tk ? x : o; x = tk ? o : x; }
                { const float o = L1; const bool tk = x > o; L1 = tk ? x : o; x = tk ? o : x; }
                { const float o = L2; const bool tk = x > o; L2 = tk ? x : o; x = tk ? o : x; }
                { const float o = L3; const bool tk = x > o; L3 = tk ? x : o; x = tk ? o : x; }
                { const float o = L4; const bool tk = x > o; L4 = tk ? x : o; x = tk ? o : x; }
                { const float o = L5; const bool tk = x > o; L5 = tk ? x : o; x = tk ? o : x; }
                { const float o = L6; const bool tk = x > o; L6 = tk ? x : o; x = tk ? o : x; }
                { const float o = L7; const bool tk = x > o; L7 = tk ? x : o; x = tk ? o : x; }
                { const float o = L8; const bool tk = x > o; L8 = tk ? x : o; x = tk ? o : x; }
                { const float o = L9; const bool tk = x > o; L9 = tk ? x : o; x = tk ? o : x; }
            }
        }
        // coalesced per-wave write: [b][slot = blockIdx.x*4+w][t][10]
        float* dst = tI + ((((size_t)b * (ntile * 4)) + (blockIdx.x * 4 + w)) * T
                           + lane) * NCANDK;
        dst[0]=L0; dst[1]=L1; dst[2]=L2; dst[3]=L3; dst[4]=L4;
        dst[5]=L5; dst[6]=L6; dst[7]=L7; dst[8]=L8; dst[9]=L9;
    }
}

// ---------------------------------------------------------------------------
// insertion networks (per-lane top-10 registers)
// ---------------------------------------------------------------------------
#define IOU_INS(J) { const float o = i##J; const bool tk = v > o; \
                     i##J = tk ? v : o; v = tk ? o : v; }
#define CST_INS(J) { const float oc = c##J; const int oi = q##J; \
                     const bool tk = (v < oc) || (v == oc && vi < oi); \
                     c##J = tk ? v : oc; q##J = tk ? vi : oi; \
                     v = tk ? oc : v; vi = tk ? oi : vi; }
#define IOU_POP { i0=i1; i1=i2; i2=i3; i3=i4; i4=i5; i5=i6; i6=i7; i7=i8; i8=i9; i9=0.0f; }
#define CST_POP { c0=c1; c1=c2; c2=c3; c3=c4; c4=c5; c5=c6; c6=c7; c7=c8; c8=c9; c9=INFINITY; \
                  q0=q1; q1=q2; q2=q3; q3=q4; q4=q5; q5=q6; q6=q7; q7=q8; q8=q9; q9=0x7fffffff; }

// ---------------------------------------------------------------------------
// kCTR helper: one candidate center-window cell -> (cost, idx, is_group1)
// ---------------------------------------------------------------------------
__device__ __forceinline__ void ctr_item(
    int id, const float* pb, const float4* bx, const float* ms,
    int cls, float x0, float y0, float x1, float y1,
    float cx, float cy, float area_t,
    float& cost, int& idx, bool& g1)
{
    cost = INFINITY; idx = 0x7fffffff; g1 = false;
    int levn, base; float s;
    if (id < 36)      { levn = 160; base = 0;     s = 8.0f;  }
    else if (id < 72) { levn = 80;  base = 25600; s = 16.0f; id -= 36; }
    else              { levn = 40;  base = 32000; s = 32.0f; id -= 72; }
    const int dy = id / 6, dx = id - dy * 6;
    const int gx = (int)floorf(cx / s - 3.0f) + dx;
    const int gy = (int)floorf(cy / s - 3.0f) + dy;
    if (gx < 0 || gx >= levn || gy < 0 || gy >= levn) return;
    const int a = base + gy * levn + gx;
    const float xc = ((float)gx + 0.5f) * s, yc = ((float)gy + 0.5f) * s;
    const bool inc = fmaxf(fabsf(xc - cx), fabsf(yc - cy)) < 2.5f * s;
    const bool inb = fminf(fminf(xc - x0, yc - y0), fminf(x1 - xc, y1 - yc)) > 0.0f;
    if (!(inc && inb)) return;
    const float4 pbox = bx[a];
    const float lx = fmaxf(x0, pbox.x), ly = fmaxf(y0, pbox.y);
    const float rx = fminf(x1, pbox.z), ry = fminf(y1, pbox.w);
    const float w = fmaxf(rx - lx, 0.0f), h = fmaxf(ry - ly, 0.0f);
    const float inter  = w * h;
    const float area_p = (pbox.z - pbox.x) * (pbox.w - pbox.y);
    const float uni = area_t + area_p - inter;
    const float iou = inter / fmaxf(uni, 1e-9f);
    const float S  = fabsf(ms[a]);
    const float zs = pb[(size_t)a * PREDC + 4 + cls];
    cost = (S - zs) + neg3ln_f(iou + 1e-8f);
    idx = a; g1 = true;
}

// ---------------------------------------------------------------------------
// kROW: per-(b,t) row kernel — no anchor scan.
//   Phase B (wave 0): center-window enumeration -> ctr top-10 cost + g1cnt;
//   Phase B'(wave 1, concurrent): merge tI row (ntile*4*10 values) -> dyn_k.
//   Phase C (all 8 waves, rare): full-A cost scan fallback (exact g3 prune).
//   Phase D: first dyn_k lanes scatter atomics into cnt/mint.
// ---------------------------------------------------------------------------
__global__ void __launch_bounds__(RTHREADS) kROW(
    const float* __restrict__ pred, const float* __restrict__ target,
    const float4* __restrict__ box4, const float* __restrict__ metaS,
    const float* __restrict__ tI,
    int* __restrict__ cnt, int* __restrict__ mint, int A, int T, int ntile)
{
    const int t    = blockIdx.x;
    const int b    = blockIdx.y;
    const int tid  = threadIdx.x;
    const int wid  = tid >> 6;
    const int lane = tid & 63;
    const int row  = b * T + t;

    __shared__ float sC[RSLOTS];
    __shared__ int   sX[RSLOTS];
    __shared__ float fC[NCANDK];
    __shared__ int   fX[NCANDK];
    __shared__ int   sFlag, sDk;

    const float* tb = target + (size_t)row * 5;
    const int   cls = (int)tb[0];
    const float x0 = tb[1], y0 = tb[2], x1 = tb[3], y1 = tb[4];
    const float area_t = (x1 - x0) * (y1 - y0);
    const float cx = (x0 + x1) * 0.5f, cy = (y0 + y1) * 0.5f;

    const float*  pb = pred  + (size_t)b * A * PREDC;
    const float4* bx = box4  + (size_t)b * A;
    const float*  ms = metaS + (size_t)b * A;

    // ---- Phase B (wave 0): center-window candidates; B' (wave 1): dyn_k ----
    if (wid == 0) {
        float e0c, e1c; int e0x, e1x; bool g0, g1b;
        ctr_item(lane, pb, bx, ms, cls, x0, y0, x1, y1, cx, cy, area_t, e0c, e0x, g0);
        if (lane < 44) {
            ctr_item(lane + 64, pb, bx, ms, cls, x0, y0, x1, y1, cx, cy, area_t, e1c, e1x, g1b);
        } else { e1c = INFINITY; e1x = 0x7fffffff; g1b = false; }

        const int g1cnt = __popcll(__ballot(g0)) + __popcll(__ballot(g1b));

        if (e1c < e0c || (e1c == e0c && e1x < e0x)) {
            const float tc = e0c; e0c = e1c; e1c = tc;
            const int   tx = e0x; e0x = e1x; e1x = tx;
        }
#pragma unroll
        for (int r = 0; r < NCANDK; ++r) {
            float v = e0c; int vi = e0x;
#pragma unroll
            for (int off = 32; off > 0; off >>= 1) {
                const float ov = __shfl_xor(v, off);
                const int   oi = __shfl_xor(vi, off);
                if (ov < v || (ov == v && oi < vi)) { v = ov; vi = oi; }
            }
            if (lane == 0) { fC[r] = v; fX[r] = vi; }
            if (e0x == vi) { e0c = e1c; e0x = e1x; e1c = INFINITY; e1x = 0x7fffffff; }
        }
        if (lane == 0) sFlag = (g1cnt >= NCANDK) ? 0 : 1;
    } else if (wid == 1) {
        // merge the row's ntile*4*10 iou values -> dyn_k
        const int NT4 = ntile * 4;
        const int n   = NT4 * NCANDK;
        float i0,i1,i2,i3,i4,i5,i6,i7,i8,i9;
        i0=i1=i2=i3=i4=i5=i6=i7=i8=i9 = 0.0f;
        for (int i = lane; i < n; i += 64) {
            const int gw = i / NCANDK;
            const int r  = i - gw * NCANDK;
            float v = tI[(((size_t)b * NT4 + gw) * T + t) * NCANDK + r];
            if (v > i9) {
                IOU_INS(0) IOU_INS(1) IOU_INS(2) IOU_INS(3) IOU_INS(4)
                IOU_INS(5) IOU_INS(6) IOU_INS(7) IOU_INS(8) IOU_INS(9)
            }
        }
        float ssum = 0.0f;
#pragma unroll
        for (int r = 0; r < NCANDK; ++r) {
            float v = i0; int vl = lane;
#pragma unroll
            for (int off = 32; off > 0; off >>= 1) {
                const float ov = __shfl_xor(v, off);
                const int   ol = __shfl_xor(vl, off);
                if (ov > v || (ov == v && ol < vl)) { v = ov; vl = ol; }
            }
            ssum += v;                   // descending order == reference sum
            if (lane == vl) IOU_POP
        }
        if (lane == 0) {
            int k = (int)ssum;           // trunc == astype(int32) for >=0
            k = k < 1 ? 1 : (k > NCANDK ? NCANDK : k);
            sDk = k;
        }
    }
    __syncthreads();

    // ---- Phase C: rare full-A fallback cost scan (exact g3 prune) ----
    if (sFlag) {
        float c0,c1,c2,c3,c4,c5,c6,c7,c8,c9;
        int   q0,q1,q2,q3,q4,q5,q6,q7,q8,q9;
        c0=c1=c2=c3=c4=c5=c6=c7=c8=c9 = INFINITY;
        q0=q1=q2=q3=q4=q5=q6=q7=q8=q9 = 0x7fffffff;

        for (int a = tid; a < A; a += RTHREADS) {
            const float m     = ms[a];
            const bool  ibanc = m > 0.0f;
            // exact prune: non-iba cost >= 1e9 - |base| (|base| << 1e6);
            // cannot enter a top-10 whose current worst is < 0.999e9.
            if (!ibanc && c9 < 0.999e9f) continue;

            const float4 pbox = bx[a];
            const float  s    = fabsf(m);
            const float  zsel = pb[(size_t)a * PREDC + 4 + cls];
            const float3 g    = anchor_geom(a);

            const float lx = fmaxf(x0, pbox.x), ly = fmaxf(y0, pbox.y);
            const float rx = fminf(x1, pbox.z), ry = fminf(y1, pbox.w);
            const float w = fmaxf(rx - lx, 0.0f), h = fmaxf(ry - ly, 0.0f);
            const float inter  = w * h;
            const float area_p = (pbox.z - pbox.x) * (pbox.w - pbox.y);
            const float uni = area_t + area_p - inter;
            const float iou = inter / fmaxf(uni, 1e-9f);

            const bool inb = fminf(fminf(g.x - x0, g.y - y0), fminf(x1 - g.x, y1 - g.y)) > 0.0f;
            const bool inc = fmaxf(fabsf(g.x - cx), fabsf(g.y - cy)) < 2.5f * g.z;

            float cost = (s - zsel) + neg3ln_f(iou + 1e-8f);
            cost = cost + 1e5f * ((inb && inc) ? 0.0f : 1.0f);
            cost = cost + 1e9f * (ibanc ? 0.0f : 1.0f);

            if (cost < c9 || (cost == c9 && a < q9)) {
                float v = cost; int vi = a;
                CST_INS(0) CST_INS(1) CST_INS(2) CST_INS(3) CST_INS(4)
                CST_INS(5) CST_INS(6) CST_INS(7) CST_INS(8) CST_INS(9)
            }
        }
#pragma unroll
        for (int r = 0; r < NCANDK; ++r) {
            float v = c0; int vi = q0;
#pragma unroll
            for (int off = 32; off > 0; off >>= 1) {
                const float ov = __shfl_xor(v, off);
                const int   oi = __shfl_xor(vi, off);
                if (ov < v || (ov == v && oi < vi)) { v = ov; vi = oi; }
            }
            if (lane == 0) { sC[wid * NCANDK + r] = v; sX[wid * NCANDK + r] = vi; }
            if (q0 == vi) CST_POP
        }
        __syncthreads();
        if (wid == 0) {
            float v0c = sC[lane]; int v0x = sX[lane];
            float v1c = (lane < RSLOTS - 64) ? sC[64 + lane] : INFINITY;
            int   v1x = (lane < RSLOTS - 64) ? sX[64 + lane] : 0x7fffffff;
            if (v1c < v0c || (v1c == v0c && v1x < v0x)) {
                const float tc = v0c; v0c = v1c; v1c = tc;
                const int   tx = v0x; v0x = v1x; v1x = tx;
            }
#pragma unroll
            for (int r = 0; r < NCANDK; ++r) {
                float v = v0c; int vi = v0x;
#pragma unroll
                for (int off = 32; off > 0; off >>= 1) {
                    const float ov = __shfl_xor(v, off);
                    const int   oi = __shfl_xor(vi, off);
                    if (ov < v || (ov == v && oi < vi)) { v = ov; vi = oi; }
                }
                if (lane == 0) { fC[r] = v; fX[r] = vi; }
                if (v0x == vi) { v0c = v1c; v0x = v1x; v1c = INFINITY; v1x = 0x7fffffff; }
            }
        }
        __syncthreads();
    }

    // ---- Phase D: scatter first dyn_k candidates (iba-masked) ----
    if (tid < sDk) {
        const int aw = fX[tid];
        if (aw != 0x7fffffff && ms[aw] > 0.0f) {
            const size_t base = (size_t)b * A;
            atomicAdd(&cnt[base + aw], 1);
            atomicMin(&mint[base + aw], t);
        }
    }
}

// ---------------------------------------------------------------------------
// Kernel C: per (b, a) — resolve matches, conflicts, write outputs.
// Output layout (floats): mm[BA] | bt[BA*4] | ot[BA] | ct[BA]
// ---------------------------------------------------------------------------
__global__ void __launch_bounds__(256) kC(
    const float* __restrict__ pred, const float* __restrict__ target,
    const float4* __restrict__ box4, const float* __restrict__ metaS,
    const int* __restrict__ cnt, const int* __restrict__ mint,
    float* __restrict__ out, int A, int T, long BAl)
{
    const int b = blockIdx.y;
    const int a = blockIdx.x * blockDim.x + threadIdx.x;
    __shared__ float tg[TMAX * 5];
    const float* tb = target + (size_t)b * T * 5;
    for (int i = threadIdx.x; i < T * 5; i += blockDim.x) tg[i] = tb[i];
    __syncthreads();
    if (a >= A) return;

    const size_t ba = (size_t)b * A + a;
    const size_t BA = (size_t)BAl;
    float*  out_mm = out;
    float4* out_bt = (float4*)(out + BA);
    float*  out_ot = out + 5 * BA;
    float*  out_ct = out + 6 * BA;

    const int c = cnt[ba];
    if (c == 0) {
        out_mm[ba] = 0.0f;
        out_bt[ba] = make_float4(0.0f, 0.0f, 0.0f, 0.0f);
        out_ot[ba] = 0.0f;
        out_ct[ba] = (float)NCLS;
        return;
    }

    const float4 pbox = box4[ba];
    const float area_p = (pbox.z - pbox.x) * (pbox.w - pbox.y);

    const bool conflict = (c > 1);
    const float* p = pred + ba * PREDC;  // only dereferenced if conflict
    float sA = 0.0f, xc = 0.0f, yc = 0.0f, stv = 0.0f;
    int ibanc = 1;
    if (conflict) {
        const float m = metaS[ba];
        sA = fabsf(m);
        ibanc = m > 0.0f ? 1 : 0;
        const float3 g = anchor_geom(a);
        xc = g.x; yc = g.y; stv = g.z;
    }

    float pmax = 0.0f;
    float bestc = INFINITY; int bestt = 0;
    for (int t = 0; t < T; ++t) {
        const float x0 = tg[t * 5 + 1], y0 = tg[t * 5 + 2];
        const float x1 = tg[t * 5 + 3], y1 = tg[t * 5 + 4];
        const float lx = fmaxf(x0, pbox.x), ly = fmaxf(y0, pbox.y);
        const float rx = fminf(x1, pbox.z), ry = fminf(y1, pbox.w);
        const float w = fmaxf(rx - lx, 0.0f), h = fmaxf(ry - ly, 0.0f);
        const float inter  = w * h;
        const float area_t = (x1 - x0) * (y1 - y0);
        const float uni = area_t + area_p - inter;
        const float iou = inter / fmaxf(uni, 1e-9f);
        pmax = fmaxf(pmax, iou);
        if (conflict) {
            const bool inb = fminf(fminf(xc - x0, yc - y0), fminf(x1 - xc, y1 - yc)) > 0.0f;
            const float cxt = (x0 + x1) * 0.5f, cyt = (y0 + y1) * 0.5f;
            const bool inc = fmaxf(fabsf(xc - cxt), fabsf(yc - cyt)) < 2.5f * stv;
            const float zsel = p[4 + (int)tg[t * 5]];
            float cost = (sA - zsel) + neg3ln_f(iou + 1e-8f);
            cost = cost + 1e5f * ((inb && inc) ? 0.0f : 1.0f);
            cost = cost + 1e9f * (ibanc ? 0.0f : 1.0f);
            if (cost < bestc) { bestc = cost; bestt = t; }
        }
    }
    const int tp = conflict ? bestt : mint[ba];

    out_mm[ba] = 1.0f;
    out_bt[ba] = make_float4(tg[tp * 5 + 1], tg[tp * 5 + 2], tg[tp * 5 + 3], tg[tp * 5 + 4]);
    out_ot[ba] = pmax;
    out_ct[ba] = tg[tp * 5 + 0];
}

// ---------------------------------------------------------------------------
extern "C" void kernel_launch(void* const* d_in, const int* in_sizes, int n_in,
                              void* d_out, int out_size, void* d_ws, size_t ws_size,
                              hipStream_t stream)
{
    const float* pred   = (const float*)d_in[0];
    const float* target = (const float*)d_in[1];
    const float* grid   = (const float*)d_in[2];
    const float* strd   = (const float*)d_in[3];

    const int A = in_sizes[3];
    const int B = in_sizes[0] / (A * PREDC);
    const int T = in_sizes[1] / (B * 5);
    const size_t BA = (size_t)B * A;
    const int ntile = (A + 255) / 256;   // 256-anchor blocks (= kA grid.x)

    // ws: box4[BA] | metaS[BA] | cnt[BA] | mint[BA] | tI[B*ntile*4*T*10]
    float4* box4  = (float4*)d_ws;
    float*  metaS = (float*)(box4 + BA);
    int*    cnt   = (int*)(metaS + BA);
    int*    mint  = cnt + BA;
    float*  tIb   = (float*)(mint + BA);

    float* out = (float*)d_out;

    dim3 gA(ntile, B);
    kA<<<gA, 256, 0, stream>>>(pred, target, grid, strd, box4, metaS, cnt, mint,
                               tIb, A, T, ntile);

    dim3 gR(T, B);
    kROW<<<gR, RTHREADS, 0, stream>>>(pred, target, box4, metaS, tIb,
                                      cnt, mint, A, T, ntile);

    dim3 gC((A + 255) / 256, B);
    kC<<<gC, 256, 0, stream>>>(pred, target, box4, metaS, cnt, mint, out, A, T, (long)BA);
}